// Round 8
// baseline (76.496 us; speedup 1.0000x reference)
//
#include <hip/hip_runtime.h>
#include <hip/hip_bf16.h>

#define EPSF 1e-7f
#define B_ 8
#define H_ 64
#define W_ 64
#define C_ 32
#define HO 58
#define WO 58
#define NF 64
#define KDIM 800

#define XBS 40      // xtb col stride (bf16): 80B -> +20 banks/col, 16B-aligned
#define RS  424     // rot row stride (bf16): 848B -> +20 banks/row, balanced b128

typedef __bf16 v8bf __attribute__((ext_vector_type(8)));
typedef float  v4f  __attribute__((ext_vector_type(4)));
typedef float  v2f  __attribute__((ext_vector_type(2)));

// ---- pack W into MFMA B-fragment order, bf16 ----
// Wp[((nt*25+kb)*64+lane)*8+j] = W[f=nt*16+(lane&15)][k=kb*32+(lane>>4)*8+j]
__global__ void k_wpack(const float* __restrict__ W, __bf16* __restrict__ Wp) {
    int t = blockIdx.x*256 + threadIdx.x;   // 51200 total
    int j = t & 7; int lane = (t >> 3) & 63; int rest = t >> 9;
    int kb = rest % 25; int nt = rest / 25;
    int f = nt*16 + (lane & 15);
    int k = kb*32 + (lane >> 4)*8 + j;
    Wp[t] = (__bf16)W[f*KDIM + k];
}

// ---- fused, K-split 2-round: stage -> angle -> [rot(a) -> MFMA(a) -> rot(b) -> MFMA(b)] ----
__global__ __launch_bounds__(256, 5)
void k_main(const float* __restrict__ x, const v8bf* __restrict__ Wp,
            const float* __restrict__ bias, float* __restrict__ out) {
    __shared__ __bf16 xtb[7][22][XBS];    // 12,320 B
    __shared__ __bf16 rot[16][RS];        // 13,568 B
    __shared__ float  SrowH[2][7][22];    //  1,232 B  -> 27,120 B total

    int tid = threadIdx.x;
    int wv = tid >> 6, lane = tid & 63;
    int m = lane & 15, q = lane >> 4;

    // XCD-aware remap: one batch b per XCD (x-slice 524 KB -> L2-resident).
    int L = blockIdx.x + 4*(blockIdx.y + 58*blockIdx.z);
    int newL = (L & 7)*232 + (L >> 3);
    int b  = newL / 232;
    int rem = newL - b*232;
    int ho = rem >> 2;
    int wt = rem & 3;

    int wo0 = wt*16;
    int npx = WO - wo0; if (npx > 16) npx = 16;   // 16,16,16,10
    int ncols = npx + 6;                          // 22 or 16

    float bv = bias[wv*16 + m];                   // hoisted off the tail

    // phase 0: all 256 threads; item = (r,c,half16ch). Coalesced 64B chunks.
    {
        int items = 7*ncols*2;                    // 308 or 224
        const float* xb = x + (size_t)((b*H_ + ho)*W_ + wo0)*C_;
        for (int e = tid; e < items; e += 256) {
            int h = e & 1; int rc = e >> 1;
            int r, c;
            if (ncols == 22) { r = rc/22; c = rc - r*22; }
            else             { r = rc >> 4; c = rc & 15; }
            const float* src = xb + (size_t)(r*W_ + c)*C_ + h*16;
            float4 vq[4];
#pragma unroll
            for (int qq = 0; qq < 4; qq++) vq[qq] = *(const float4*)(src + qq*4);
            float s = 0.f;
#pragma unroll
            for (int qq = 0; qq < 4; qq++) s += vq[qq].x + vq[qq].y + vq[qq].z + vq[qq].w;
            SrowH[h][r][c] = s;
#pragma unroll
            for (int h8 = 0; h8 < 2; h8++) {
                v8bf o;
                o[0]=(__bf16)vq[h8*2].x;   o[1]=(__bf16)vq[h8*2].y;
                o[2]=(__bf16)vq[h8*2].z;   o[3]=(__bf16)vq[h8*2].w;
                o[4]=(__bf16)vq[h8*2+1].x; o[5]=(__bf16)vq[h8*2+1].y;
                o[6]=(__bf16)vq[h8*2+1].z; o[7]=(__bf16)vq[h8*2+1].w;
                *(v8bf*)&xtb[r][c][h*16 + h8*8] = o;
            }
        }
    }
    __syncthreads();

    // phase 2 (wave-parallel, in-register): lane owns pxl = 4*wv + q; 16 lanes
    // per pixel (slot = m) split the 49 window terms, shfl_xor reduce.
    int pxl = wv*4 + q;
    float den = 0.f, crn = 0.f, ccn = 0.f;
#pragma unroll
    for (int k = 0; k < 4; k++) {
        int t = m + 16*k;
        if (t < 49) {
            int i = t / 7, j = t - 7*i;
            float v = SrowH[0][i][pxl + j] + SrowH[1][i][pxl + j];
            den += v; crn += v*(float)i; ccn += v*(float)j;
        }
    }
#pragma unroll
    for (int msk = 1; msk <= 8; msk <<= 1) {
        den += __shfl_xor(den, msk);
        crn += __shfl_xor(crn, msk);
        ccn += __shfl_xor(ccn, msk);
    }
    float pc, ps, pxo, pyo;
    {
        float dt = den + EPSF;
        float cr = crn/dt - 3.0f;
        float cx = ccn/dt - 3.0f + EPSF;
        float r2 = cr*cr + cx*cx;
        float inv = r2 > 0.f ? rsqrtf(r2) : 0.f;
        float c = r2 > 0.f ? cx*inv : 1.0f;
        float s = cr*inv;
        const float scale = 1.0f + EPSF;
        pc  = c/scale; ps = s/scale;
        pxo = (6.0f - (c*6.0f - s*6.0f))*0.5f/scale;
        pyo = (6.0f - (s*6.0f + c*6.0f))*0.5f/scale;
    }

    // bilinear for (pxl,pos) -> rot[pxl][slot*32 ...]
    auto do_rot = [&](int pos, int slot) {
        int py = pos/5; int yy = py + 1; int xx = pos - py*5 + 1;
        float xin = pc*(float)xx - ps*(float)yy + pxo;
        float yin = ps*(float)xx + pc*(float)yy + pyo;
        float x0f = floorf(xin), y0f = floorf(yin);
        float wx1 = xin - x0f, wx0 = 1.0f - wx1;
        float wy1 = yin - y0f, wy0 = 1.0f - wy1;
        int ix0 = (int)x0f, iy0 = (int)y0f;
        int ix1 = ix0 + 1,  iy1 = iy0 + 1;

        const __bf16* bp[4]; float wgt[4];
        auto mkcorner = [&](int yi, int xi, float w, int idx) {
            bool valid = (xi >= 0) & (xi < 7) & (yi >= 0) & (yi < 7);
            int cy = yi < 0 ? 0 : (yi > 6 ? 6 : yi);
            int cx2 = xi < 0 ? 0 : (xi > 6 ? 6 : xi);
            bp[idx]  = &xtb[cy][pxl + cx2][0];
            wgt[idx] = valid ? w : 0.0f;
        };
        mkcorner(iy0, ix0, wy0*wx0, 0);
        mkcorner(iy0, ix1, wy0*wx1, 1);
        mkcorner(iy1, ix0, wy1*wx0, 2);
        mkcorner(iy1, ix1, wy1*wx1, 3);

        v2f acc[16];
#pragma unroll
        for (int i = 0; i < 16; i++) acc[i] = (v2f){0.f, 0.f};
#pragma unroll
        for (int cn = 0; cn < 4; cn++) {
            const __bf16* src = bp[cn];
            v2f wq2 = (v2f){wgt[cn], wgt[cn]};
#pragma unroll
            for (int q8 = 0; q8 < 4; q8++) {
                union { v8bf v; unsigned u[4]; } uv;
                uv.v = *(const v8bf*)(src + q8*8);
#pragma unroll
                for (int d = 0; d < 4; d++) {
                    v2f val = (v2f){ __uint_as_float(uv.u[d] << 16),
                                     __uint_as_float(uv.u[d] & 0xffff0000u) };
                    acc[q8*4 + d] += wq2 * val;   // v_pk_fma_f32
                }
            }
        }
#pragma unroll
        for (int q8 = 0; q8 < 4; q8++) {
            v8bf o;
#pragma unroll
            for (int d = 0; d < 4; d++) {
                o[2*d]   = (__bf16)acc[q8*4 + d].x;
                o[2*d+1] = (__bf16)acc[q8*4 + d].y;
            }
            *(v8bf*)&rot[pxl][slot*32 + q8*8] = o;
        }
    };

    const v8bf* wp = Wp + (size_t)wv*25*64 + lane;
    v4f acc0 = {0.f, 0.f, 0.f, 0.f};
    v4f acc1 = {0.f, 0.f, 0.f, 0.f};

    // ---- round a: positions 0..12 ----
    if (m < 13) do_rot(m, m);
    v8bf bfA[13];
#pragma unroll
    for (int kb = 0; kb < 13; kb++) bfA[kb] = wp[kb*64];   // hides under barrier
    __syncthreads();
#pragma unroll
    for (int kb = 0; kb < 13; kb++) {
        v8bf a = *(const v8bf*)&rot[m][kb*32 + q*8];
        if (kb & 1) acc1 = __builtin_amdgcn_mfma_f32_16x16x32_bf16(a, bfA[kb], acc1, 0, 0, 0);
        else        acc0 = __builtin_amdgcn_mfma_f32_16x16x32_bf16(a, bfA[kb], acc0, 0, 0, 0);
    }
    __syncthreads();   // all reads of rot done before round b overwrites

    // ---- round b: positions 13..24 ----
    if (m < 12) do_rot(13 + m, m);
    v8bf bfB[12];
#pragma unroll
    for (int kb = 0; kb < 12; kb++) bfB[kb] = wp[(13 + kb)*64];
    __syncthreads();
#pragma unroll
    for (int kb = 0; kb < 12; kb++) {
        v8bf a = *(const v8bf*)&rot[m][kb*32 + q*8];
        if (kb & 1) acc1 = __builtin_amdgcn_mfma_f32_16x16x32_bf16(a, bfB[kb], acc1, 0, 0, 0);
        else        acc0 = __builtin_amdgcn_mfma_f32_16x16x32_bf16(a, bfB[kb], acc0, 0, 0, 0);
    }

    int f = wv*16 + m;          // C/D col = lane&15 -> filter
    int pixbase = (b*HO + ho)*WO + wo0;
#pragma unroll
    for (int r = 0; r < 4; r++) {
        int px = q*4 + r;       // C/D row = (lane>>4)*4 + reg -> pixel
        if (px < npx) out[(size_t)(pixbase + px)*NF + f] = acc0[r] + acc1[r] + bv;
    }
}

extern "C" void kernel_launch(void* const* d_in, const int* in_sizes, int n_in,
                              void* d_out, int out_size, void* d_ws, size_t ws_size,
                              hipStream_t stream) {
    const float* x    = (const float*)d_in[0];
    const float* W    = (const float*)d_in[1];
    const float* bias = (const float*)d_in[2];
    float* out = (float*)d_out;
    __bf16* Wp = (__bf16*)d_ws;                    // 102,400 B

    k_wpack<<<dim3(200), 256, 0, stream>>>(W, Wp);
    k_main<<<dim3(4, HO, B_), 256, 0, stream>>>(x, (const v8bf*)Wp, bias, out);
}